// Round 1
// baseline (531.792 us; speedup 1.0000x reference)
//
#include <hip/hip_runtime.h>
#include <hip/hip_bf16.h>

// BoxModelTriples: M=8, B=200000, D=32, N=100000
// box_param: (M, B, 2, D) float32   -> 102,400,000 floats
// weights:   (M,)          float32
// ids:       (N, 4)        int32    (JAX default x64-disabled -> int32)
// out:       (N,)          float32
//
// One wave (64 lanes) per output row n.
// Lane layout: msub = lane>>5 (covers 2 m values per pass), d = lane&31.
// Loop mb = 0,2,4,6 -> m = mb + msub covers all 8 mixture components.
// Product over D=32 via 5-step shfl_xor butterfly within each 32-lane half;
// weighted sums accumulated per half, combined with a final xor-32 add.

#define MM 8
#define BB 200000
#define DD 32

__global__ __launch_bounds__(256) void box_triples_kernel(
    const float* __restrict__ box,   // (M,B,2,D)
    const float* __restrict__ wts,   // (M,)
    const int*   __restrict__ ids,   // (N,4) int32
    float*       __restrict__ out,   // (N,)
    int N)
{
    const int lane = threadIdx.x & 63;
    const int wave = threadIdx.x >> 6;
    const int n = blockIdx.x * (blockDim.x >> 6) + wave;
    if (n >= N) return;   // wave-uniform

    // ---- softmax over 8 weights (wave-uniform scalar work) ----
    float wraw[MM];
    #pragma unroll
    for (int m = 0; m < MM; ++m) wraw[m] = wts[m];
    float wmax = wraw[0];
    #pragma unroll
    for (int m = 1; m < MM; ++m) wmax = fmaxf(wmax, wraw[m]);
    float esum = 0.f;
    float e[MM];
    #pragma unroll
    for (int m = 0; m < MM; ++m) { e[m] = expf(wraw[m] - wmax); esum += e[m]; }
    const float einv = 1.0f / esum;

    // ---- ids ----
    const int4 idv = ((const int4*)ids)[n];
    const int i0 = idv.x, i1 = idv.y, i2 = idv.z;

    const int msub = lane >> 5;   // 0 or 1
    const int d    = lane & 31;

    float sA = 0.f, sAB = 0.f, sABC = 0.f;

    #pragma unroll
    for (int mb = 0; mb < MM; mb += 2) {
        const int m = mb + msub;
        // element offsets: ((m*B + b)*2 + s)*D + d
        const int rowA = (m * BB + i0) * (2 * DD) + d;
        const int rowB = (m * BB + i1) * (2 * DD) + d;
        const int rowC = (m * BB + i2) * (2 * DD) + d;

        float zA = box[rowA], ZA = box[rowA + DD];
        float zB = box[rowB], ZB = box[rowB + DD];
        float zC = box[rowC], ZC = box[rowC + DD];

        // clip to [0,1]
        zA = fminf(fmaxf(zA, 0.f), 1.f);  ZA = fminf(fmaxf(ZA, 0.f), 1.f);
        zB = fminf(fmaxf(zB, 0.f), 1.f);  ZB = fminf(fmaxf(ZB, 0.f), 1.f);
        zC = fminf(fmaxf(zC, 0.f), 1.f);  ZC = fminf(fmaxf(ZC, 0.f), 1.f);

        const float zAB  = fmaxf(zA, zB);
        const float ZAB  = fminf(ZA, ZB);
        const float zABC = fmaxf(zAB, zC);
        const float ZABC = fminf(ZAB, ZC);

        float sdA   = fmaxf(ZA   - zA,   0.f);
        float sdAB  = fmaxf(ZAB  - zAB,  0.f);
        float sdABC = fmaxf(ZABC - zABC, 0.f);

        // product over the 32 d-lanes within each half
        #pragma unroll
        for (int off = 1; off < 32; off <<= 1) {
            sdA   *= __shfl_xor(sdA,   off);
            sdAB  *= __shfl_xor(sdAB,  off);
            sdABC *= __shfl_xor(sdABC, off);
        }

        // per-half weight (avoid lane-varying index into register array)
        const float w_lo = e[mb]     * einv;
        const float w_hi = e[mb + 1] * einv;
        const float wm = msub ? w_hi : w_lo;

        sA   += wm * sdA;
        sAB  += wm * sdAB;
        sABC += wm * sdABC;
    }

    // combine the two halves (m = mb vs mb+1)
    sA   += __shfl_xor(sA,   32);
    sAB  += __shfl_xor(sAB,  32);
    sABC += __shfl_xor(sABC, 32);

    const float TINY = 1.1754943508222875e-38f;
    float res;
    if (i1 != i2) {
        res = (sABC + TINY) / (sAB + TINY);      // three_cond
    } else if (i0 != i1) {
        res = (sAB + TINY) / (sA + TINY);        // two_cond
    } else {
        res = sA;                                 // unary (universe_vol = 1)
    }

    if (lane == 0) out[n] = res;
}

extern "C" void kernel_launch(void* const* d_in, const int* in_sizes, int n_in,
                              void* d_out, int out_size, void* d_ws, size_t ws_size,
                              hipStream_t stream) {
    const float* box = (const float*)d_in[0];
    const float* wts = (const float*)d_in[1];
    const int*   ids = (const int*)d_in[2];
    float* out = (float*)d_out;
    const int N = out_size;                 // 100000

    const int wavesPerBlock = 4;            // 256 threads
    const int blocks = (N + wavesPerBlock - 1) / wavesPerBlock;
    box_triples_kernel<<<blocks, 256, 0, stream>>>(box, wts, ids, out, N);
}

// Round 2
// 528.426 us; speedup vs baseline: 1.0064x; 1.0064x over previous
//
#include <hip/hip_runtime.h>
#include <hip/hip_bf16.h>

// BoxModelTriples: M=8, B=200000, D=32, N=100000
// box_param: (M, B, 2, D) float32
// weights:   (M,)          float32
// ids:       (N, 4)        int32
// out:       (N,)          float32
//
// One wave (64 lanes) per output row n.
// Lane layout: m = lane>>3 (all 8 mixture components in parallel),
//              t = lane&7, covering d = 4t..4t+3 via float4 loads.
// 6 global_load_dwordx4 per wave (3 boxes x {z,Z}), all independent.
// Product over d: 4 in-lane mults + 3-step shfl_xor butterfly over t.
// Weighted sum over m: per-lane softmax weight + 3-step shfl_xor add.

#define MM 8
#define BB 200000
#define DD 32

__global__ __launch_bounds__(256) void box_triples_kernel(
    const float* __restrict__ box,   // (M,B,2,D)
    const float* __restrict__ wts,   // (M,)
    const int*   __restrict__ ids,   // (N,4) int32
    float*       __restrict__ out,   // (N,)
    int N)
{
    const int lane = threadIdx.x & 63;
    const int wave = threadIdx.x >> 6;
    const int n = blockIdx.x * (blockDim.x >> 6) + wave;
    if (n >= N) return;   // wave-uniform

    const int m = lane >> 3;   // 0..7
    const int t = lane & 7;    // 0..7  (d = 4t..4t+3)

    // ---- ids (broadcast load, 16 B same address per wave) ----
    const int4 idv = ((const int4*)ids)[n];
    const int i0 = idv.x, i1 = idv.y, i2 = idv.z;

    // ---- gather: 6 independent dwordx4 loads ----
    const int baseA = (m * BB + i0) * (2 * DD) + t * 4;
    const int baseB = (m * BB + i1) * (2 * DD) + t * 4;
    const int baseC = (m * BB + i2) * (2 * DD) + t * 4;

    const float4 zA4 = *(const float4*)(box + baseA);
    const float4 ZA4 = *(const float4*)(box + baseA + DD);
    const float4 zB4 = *(const float4*)(box + baseB);
    const float4 ZB4 = *(const float4*)(box + baseB + DD);
    const float4 zC4 = *(const float4*)(box + baseC);
    const float4 ZC4 = *(const float4*)(box + baseC + DD);

    // ---- per-lane softmax weight for this m (butterfly over m dim) ----
    float wl = wts[m];
    float wmax = wl;
    #pragma unroll
    for (int off = 8; off < 64; off <<= 1) wmax = fmaxf(wmax, __shfl_xor(wmax, off));
    float ew = __expf(wl - wmax);
    float esum = ew;
    #pragma unroll
    for (int off = 8; off < 64; off <<= 1) esum += __shfl_xor(esum, off);
    const float w = ew / esum;

    // ---- per-component volume contributions ----
    float pA = 1.f, pAB = 1.f, pABC = 1.f;
    #define CL(x) fminf(fmaxf((x), 0.f), 1.f)
    #define COMP(c) { \
        const float za = CL(zA4.c), Za = CL(ZA4.c); \
        const float zb = CL(zB4.c), Zb = CL(ZB4.c); \
        const float zc = CL(zC4.c), Zc = CL(ZC4.c); \
        const float zab  = fmaxf(za, zb),  Zab  = fminf(Za, Zb); \
        const float zabc = fmaxf(zab, zc), Zabc = fminf(Zab, Zc); \
        pA   *= fmaxf(Za   - za,   0.f); \
        pAB  *= fmaxf(Zab  - zab,  0.f); \
        pABC *= fmaxf(Zabc - zabc, 0.f); \
    }
    COMP(x) COMP(y) COMP(z) COMP(w)
    #undef COMP
    #undef CL

    // ---- product over t (8 lanes per m group) ----
    #pragma unroll
    for (int off = 1; off < 8; off <<= 1) {
        pA   *= __shfl_xor(pA,   off);
        pAB  *= __shfl_xor(pAB,  off);
        pABC *= __shfl_xor(pABC, off);
    }

    // ---- weighted sum over m ----
    float sA = w * pA, sAB = w * pAB, sABC = w * pABC;
    #pragma unroll
    for (int off = 8; off < 64; off <<= 1) {
        sA   += __shfl_xor(sA,   off);
        sAB  += __shfl_xor(sAB,  off);
        sABC += __shfl_xor(sABC, off);
    }

    const float TINY = 1.1754943508222875e-38f;
    float res;
    if (i1 != i2) {
        res = (sABC + TINY) / (sAB + TINY);      // three_cond
    } else if (i0 != i1) {
        res = (sAB + TINY) / (sA + TINY);        // two_cond
    } else {
        res = sA;                                 // unary (universe_vol = 1)
    }

    if (lane == 0) out[n] = res;
}

extern "C" void kernel_launch(void* const* d_in, const int* in_sizes, int n_in,
                              void* d_out, int out_size, void* d_ws, size_t ws_size,
                              hipStream_t stream) {
    const float* box = (const float*)d_in[0];
    const float* wts = (const float*)d_in[1];
    const int*   ids = (const int*)d_in[2];
    float* out = (float*)d_out;
    const int N = out_size;                 // 100000

    const int wavesPerBlock = 4;            // 256 threads
    const int blocks = (N + wavesPerBlock - 1) / wavesPerBlock;
    box_triples_kernel<<<blocks, 256, 0, stream>>>(box, wts, ids, out, N);
}